// Round 5
// baseline (838.346 us; speedup 1.0000x reference)
//
#include <hip/hip_runtime.h>

// FGIAN BiLSTM+attention. R9: k_scan restructured as 8-wave K-SPLIT.
// Post-mortem R6/R8: per-CU LDS pipe saturated by broadcast reads (176 DS
// ops/CU-step ~= measured 1490cy; VALUBusy 27.8%); R8's reg-batch never
// materialized (VGPR stayed 88). R5 (readlane, 297us) was issue-bound with
// ~600cy unhidden latency at only 2 waves/SIMD. Fix the STRUCTURE:
//  - 8 waves/task: waves 0-3 k=0..31, waves 4-7 k=32..63 (32 named weight
//    scalars/lane, half of R5); kh1 writes partial to LDS, kh0 adds + act.
//  - 4096 waves total -> 4 waves/SIMD (waves_per_eu(4,4), 128-VGPR budget).
//  - quad-gather i/f/g/o via DPP quad_perm (VALU) instead of ds_swizzle
//    (removes 4 LDS round-trips from the serial act path).
// Everything outside k_scan unchanged.

#define B 128
#define TBODY 512
#define TPUN 256
#define EMB 300
#define EMBP 320
#define VOCAB 50000
#define HID 64
#define G4 256
#define NG 512
#define DM 128

typedef __attribute__((ext_vector_type(8))) short bf16x8;
typedef __attribute__((ext_vector_type(4))) float floatx4;
typedef unsigned short u16;

// ---- workspace layout (bytes) ----
#define OFF_XPB   0u                    // f32 [B*TBODY*NG] = 134217728
#define OFF_XPP   134217728u            // f32 [B*TPUN*NG]  =  67108864
#define OFF_BODYM 201326592u            // f32 [B*TBODY*DM] =  33554432
#define OFF_PUNM  234881024u            // f32 [B*TPUN*DM]  =  16777216
#define OFF_SMALL 251658240u
// overlays in xpB (dead after k_scan):
#define OFF_ABODY (OFF_XPB + 0u)
#define OFF_APUN  (OFF_XPB + 262144u)
#define OFF_MT    (OFF_XPB + 393216u)
#define OFF_MP    (OFF_XPB + 655360u)
#define OFF_COLP  (OFF_XPB + 786432u)
// overlays in bodyM/punM (dead until memset AFTER gemms):
#define OFF_EMBB  OFF_BODYM             // bf16 [VOCAB*EMBP] = 32000000
#define OFF_WCB   OFF_PUNM
#define OFF_WCP   (OFF_PUNM + 327680u)
#define OFF_BIASB (OFF_PUNM + 655360u)
#define OFF_BIASP (OFF_PUNM + 657408u)
#define OFF_LENS  OFF_SMALL
#define OFF_FEAT  (OFF_SMALL + 1024u)

__device__ inline u16 f2bf(float v) {
    unsigned int u = __float_as_uint(v);
    unsigned int r = (u + 0x7FFFu + ((u >> 16) & 1u)) >> 16;  // RNE
    return (u16)r;
}

__device__ inline void gload_lds16(const void* g, void* l) {
    __builtin_amdgcn_global_load_lds(
        (const __attribute__((address_space(1))) unsigned int*)g,
        (__attribute__((address_space(3))) unsigned int*)l, 16, 0, 0);
}

#define RL(v, k) __int_as_float(__builtin_amdgcn_readlane(__float_as_int(v), k))
// quad_perm broadcast of quad-lane gg (0..3): ctrl = gg*0x55
#define QBC(v, gg) __int_as_float(__builtin_amdgcn_update_dpp( \
    0, __float_as_int(v), (gg) * 0x55, 0xF, 0xF, true))

// ---------------- lens ----------------
__global__ __launch_bounds__(256) void k_lens(const int* __restrict__ bidx,
                                              const int* __restrict__ pidx,
                                              int* __restrict__ lens) {
    int j = blockIdx.x, tid = threadIdx.x;
    const int* src; int n;
    if (j < B) { src = bidx + (size_t)j * TBODY; n = TBODY; }
    else       { src = pidx + (size_t)(j - B) * TPUN; n = TPUN; }
    int c = 0;
    for (int t = tid; t < n; t += 256) c += (src[t] != 0) ? 1 : 0;
    for (int o = 32; o; o >>= 1) c += __shfl_xor(c, o, 64);
    __shared__ int red[4];
    if ((tid & 63) == 0) red[tid >> 6] = c;
    __syncthreads();
    if (tid == 0) lens[j] = red[0] + red[1] + red[2] + red[3];
}

// ---------------- prep: emb -> bf16 padded ----------------
__global__ __launch_bounds__(256) void k_prep_emb(const float* __restrict__ emb,
                                                  u16* __restrict__ embb) {
    int e = blockIdx.x * 256 + threadIdx.x;  // exactly VOCAB*EMBP
    int row = e / EMBP, d = e - row * EMBP;
    float v = (d < EMB) ? emb[(size_t)row * EMB + d] : 0.f;
    embb[e] = f2bf(v);
}

// ---------------- prep: weights concat f/b -> bf16 padded + biases ----------------
__global__ __launch_bounds__(256) void k_prep_w(
    const float* __restrict__ bWih_f, const float* __restrict__ bWih_b,
    const float* __restrict__ bb_f, const float* __restrict__ bb_b,
    const float* __restrict__ pWih_f, const float* __restrict__ pWih_b,
    const float* __restrict__ pb_f, const float* __restrict__ pb_b,
    u16* __restrict__ Wcb, u16* __restrict__ Wcp,
    float* __restrict__ biasb, float* __restrict__ biasp) {
    int e = blockIdx.x * 256 + threadIdx.x;
    const int WSZ = NG * EMBP;  // 163840
    if (e < WSZ) {
        int g = e / EMBP, d = e - g * EMBP;
        float v = 0.f;
        if (d < EMB) v = (g < G4) ? bWih_f[g * EMB + d] : bWih_b[(g - G4) * EMB + d];
        Wcb[e] = f2bf(v);
    } else if (e < 2 * WSZ) {
        int ee = e - WSZ;
        int g = ee / EMBP, d = ee - g * EMBP;
        float v = 0.f;
        if (d < EMB) v = (g < G4) ? pWih_f[g * EMB + d] : pWih_b[(g - G4) * EMB + d];
        Wcp[ee] = f2bf(v);
    } else if (e < 2 * WSZ + NG) {
        int g = e - 2 * WSZ;
        biasb[g] = (g < G4) ? bb_f[g] : bb_b[g - G4];
    } else if (e < 2 * WSZ + 2 * NG) {
        int g = e - 2 * WSZ - NG;
        biasp[g] = (g < G4) ? pb_f[g] : pb_b[g - G4];
    }
}

// ---------------- 128x128 bf16 MFMA GEMM, global_load_lds staging ----------------
__global__ __launch_bounds__(256) void k_gemm(const int* __restrict__ idx,
                                              const u16* __restrict__ embb,
                                              const u16* __restrict__ Wc,
                                              const float* __restrict__ biasc,
                                              float* __restrict__ out) {
    __shared__ u16 As[128 * 32];
    __shared__ u16 Bs[128 * 32];
    int tid = threadIdx.x, wave = tid >> 6, lane = tid & 63;
    int m0 = blockIdx.x * 128, g0 = blockIdx.y * 128;

    const u16* agp[2]; const u16* bgp[2];
    u16* asd[2]; u16* bsd[2];
#pragma unroll
    for (int j = 0; j < 2; j++) {
        int rbase = wave * 32 + j * 16;
        int r = rbase + (lane >> 2);
        int clog = (lane & 3) ^ (r & 3);
        int arow = idx[m0 + r];
        agp[j] = embb + (size_t)arow * EMBP + clog * 8;
        bgp[j] = Wc + (size_t)(g0 + r) * EMBP + clog * 8;
        asd[j] = As + rbase * 32;
        bsd[j] = Bs + rbase * 32;
    }

    int l15 = lane & 15, quad = lane >> 4;
    int mt0 = (wave >> 1) * 4, nt0 = (wave & 1) * 4;
    const u16* ard[4]; const u16* brd[4];
#pragma unroll
    for (int a = 0; a < 4; a++) {
        int r = (mt0 + a) * 16 + l15;
        ard[a] = As + r * 32 + ((quad ^ (r & 3)) * 8);
        int n = (nt0 + a) * 16 + l15;
        brd[a] = Bs + n * 32 + ((quad ^ (n & 3)) * 8);
    }

    floatx4 acc[4][4];
#pragma unroll
    for (int a = 0; a < 4; a++)
#pragma unroll
        for (int c = 0; c < 4; c++) acc[a][c] = (floatx4){0.f, 0.f, 0.f, 0.f};

    for (int k0 = 0; k0 < EMBP; k0 += 32) {
#pragma unroll
        for (int j = 0; j < 2; j++) {
            gload_lds16(agp[j] + k0, asd[j]);
            gload_lds16(bgp[j] + k0, bsd[j]);
        }
        __syncthreads();
        bf16x8 af[4], bfr[4];
#pragma unroll
        for (int a = 0; a < 4; a++) { af[a] = *(const bf16x8*)ard[a]; bfr[a] = *(const bf16x8*)brd[a]; }
#pragma unroll
        for (int a = 0; a < 4; a++)
#pragma unroll
            for (int c = 0; c < 4; c++)
                acc[a][c] = __builtin_amdgcn_mfma_f32_16x16x32_bf16(af[a], bfr[c], acc[a][c], 0, 0, 0);
        __syncthreads();
    }

#pragma unroll
    for (int c = 0; c < 4; c++) {
        int gcol = g0 + (nt0 + c) * 16 + l15;
        float bv = biasc[gcol];
#pragma unroll
        for (int a = 0; a < 4; a++) {
            int row0 = m0 + (mt0 + a) * 16 + quad * 4;
#pragma unroll
            for (int rg = 0; rg < 4; rg++)
                out[(size_t)(row0 + rg) * NG + gcol] = acc[a][c][rg] + bv;
        }
    }
}

// ---------------- LSTM scans: 1 block (8 waves, K-SPLIT) per (seq,dir,b) ----
// wave wv: kh = wv>>2 (k-half), ug = wv&3 (unit group). lane l: gate g=l&3,
// unit u = ug*16 + (l>>2). Each lane holds 32 weight scalars (its k-half).
// Per step: 1 replica ds_read_b128 of h, 32 readlane + 32 fma, kh1 writes
// partial to LDS (conflict-free part[ug*64+l]), barrier, kh0 adds + act
// (DPP quad_perm gather of i/f/g/o), h publish, barrier.
#define DECLW(j) float Wk##j##0 = vw[4*j], Wk##j##1 = vw[4*j+1], \
                       Wk##j##2 = vw[4*j+2], Wk##j##3 = vw[4*j+3];
#define STEP4H(jj) \
    a0 = fmaf(RL(hq.x, j0 + jj), Wk##jj##0, a0); \
    a1 = fmaf(RL(hq.y, j0 + jj), Wk##jj##1, a1); \
    a2 = fmaf(RL(hq.z, j0 + jj), Wk##jj##2, a2); \
    a3 = fmaf(RL(hq.w, j0 + jj), Wk##jj##3, a3);

__global__ __attribute__((amdgpu_flat_work_group_size(512, 512),
                          amdgpu_waves_per_eu(4, 4))) void k_scan(
    const float* __restrict__ xpB, const float* __restrict__ xpP,
    float* __restrict__ bodyM, float* __restrict__ punM,
    const int* __restrict__ lens,
    const float* __restrict__ bWhh_f, const float* __restrict__ bWhh_b,
    const float* __restrict__ pWhh_f, const float* __restrict__ pWhh_b) {
    int task = blockIdx.x, tid = threadIdx.x;
    int isPun = task >> 8;
    int sub = task & 255;
    int b = sub & 127, dir = sub >> 7;
    int T = isPun ? TPUN : TBODY;
    int len = lens[(isPun ? B : 0) + b];
    int wv = tid >> 6, l = tid & 63;
    int kh = wv >> 2;            // 0: k=0..31, 1: k=32..63
    int ug = wv & 3;             // unit group (16 units)
    int g = l & 3, q = l >> 2;
    int u = ug * 16 + q;
    const float* xp = (isPun ? xpP : xpB) + (size_t)b * T * NG + dir * G4;
    float* outp = (isPun ? punM : bodyM) + (size_t)b * T * DM + dir * HID;
    const float* Whh = isPun ? (dir ? pWhh_b : pWhh_f) : (dir ? bWhh_b : bWhh_f);

    // 32 weights (this lane's gate row, its k-half) as named scalars;
    // volatile load = exactly once, not sinkable.
    const volatile float* vw = Whh + (size_t)(g * 64 + u) * 64 + kh * 32;
    DECLW(0) DECLW(1) DECLW(2) DECLW(3)
    DECLW(4) DECLW(5) DECLW(6) DECLW(7)

    __shared__ __align__(16) float hbuf[2][64];
    __shared__ float part[256];
    if (tid < 64) hbuf[0][tid] = 0.f;
    __syncthreads();
    if (len <= 0) return;

    int j0 = kh * 8;                       // this wave's h-quad base
    const float* xg = xp + g * 64 + u;     // gate preact column (kh0 only)
    float c = 0.f;
    float x_cur = 0.f;
    if (!kh) x_cur = xg[(size_t)(dir ? (len - 1) : 0) * NG];
    for (int s = 0; s < len; ++s) {
        int p = dir ? (len - 1 - s) : s;
        float xv = x_cur;                  // 0 for kh1 waves
        if (!kh) {
            // branchless prefetch of next step's x (clamped, always valid)
            int pn = dir ? (len - 2 - s) : (s + 1);
            pn = min(max(pn, 0), T - 1);
            x_cur = xg[(size_t)pn * NG];
        }
        // replica read: lane (l&15) reads h[4*(l&15) .. +3] (4-way broadcast)
        float4 hq = *(const float4*)(&hbuf[s & 1][(l & 15) * 4]);
        float a0 = xv, a1 = 0.f, a2 = 0.f, a3 = 0.f;
        STEP4H(0) STEP4H(1) STEP4H(2) STEP4H(3)
        STEP4H(4) STEP4H(5) STEP4H(6) STEP4H(7)
        float pre = (a0 + a1) + (a2 + a3);
        if (kh) part[ug * 64 + l] = pre;   // consecutive addrs, conflict-free
        __syncthreads();
        if (!kh) {
            pre += part[ug * 64 + l];
            // branchless: g==2 -> tanh(pre), else sigmoid(pre)
            bool isg = (g == 2);
            float t_in = isg ? (2.f * pre) : (-pre);
            float e = __expf(t_in);
            float r = __builtin_amdgcn_rcpf(1.f + e);
            float val = isg ? fmaf(-2.f, r, 1.f) : r;
            // quad gather i,f,g,o via DPP quad_perm (VALU, no LDS round-trip)
            float vi = QBC(val, 0);
            float vf = QBC(val, 1);
            float vg = QBC(val, 2);
            float vo = QBC(val, 3);
            c = fmaf(vf, c, vi * vg);
            float th = fmaf(-2.f, __builtin_amdgcn_rcpf(1.f + __expf(2.f * c)), 1.f);
            float h = vo * th;
            if (g == 0) {
                hbuf[(s & 1) ^ 1][u] = h;
                outp[(size_t)p * DM + u] = h;
            }
        }
        __syncthreads();
    }
}

// ---------------- a_t = body_M.w1, b_p = pun_M.w2 (one wave per row) ----------------
__global__ __launch_bounds__(256) void k_rowdot(const float* __restrict__ bodyM,
                                                const float* __restrict__ punM,
                                                const float* __restrict__ w_u,
                                                float* __restrict__ a_body,
                                                float* __restrict__ a_pun) {
    int wid = (blockIdx.x * 256 + threadIdx.x) >> 6;
    int lane = threadIdx.x & 63;
    const int NB = B * TBODY;
    const float* src; const float* wv; float* dst;
    if (wid < NB) { src = bodyM + (size_t)wid * DM; wv = w_u; dst = a_body + wid; }
    else { src = punM + (size_t)(wid - NB) * DM; wv = w_u + DM; dst = a_pun + (wid - NB); }
    float2 v = ((const float2*)src)[lane];
    float2 w = ((const float2*)wv)[lane];
    float s = v.x * w.x + v.y * w.y;
    for (int o = 32; o; o >>= 1) s += __shfl_xor(s, o, 64);
    if (lane == 0) *dst = s;
}

// ---------------- align tile: m_t (full) + col partial maxes ----------------
__global__ __launch_bounds__(256) void k_align(
    const float* __restrict__ bodyM, const float* __restrict__ punM,
    const float* __restrict__ a_body, const float* __restrict__ a_pun,
    const float* __restrict__ w_u,
    float* __restrict__ m_t, float* __restrict__ colpart) {
    __shared__ float bw[64 * 132];
    __shared__ float pu[64 * 129];
    __shared__ float colred[64 * 16];
    int tid = threadIdx.x;
    int tt = blockIdx.x, b = blockIdx.y;
    int t0 = tt * 64;
    int ti = tid >> 4, pi = tid & 15;
    const float* w3 = w_u + 2 * DM;
    const float* bsrc = bodyM + ((size_t)b * TBODY + t0) * DM;
#pragma unroll
    for (int j = 0; j < 8; j++) {
        int e = tid + 256 * j;
        int i = e >> 5, c4 = e & 31;
        float4 v = *(const float4*)(bsrc + i * DM + c4 * 4);
        float4 wv = *(const float4*)(w3 + c4 * 4);
        v.x *= wv.x; v.y *= wv.y; v.z *= wv.z; v.w *= wv.w;
        *(float4*)(bw + i * 132 + c4 * 4) = v;
    }
    float aB[4];
#pragma unroll
    for (int a = 0; a < 4; a++) aB[a] = a_body[(size_t)b * TBODY + t0 + ti * 4 + a];
    float mrun[4] = {-1e30f, -1e30f, -1e30f, -1e30f};
    for (int pc = 0; pc < 4; pc++) {
        __syncthreads();
        const float* psrc = punM + ((size_t)b * TPUN + pc * 64) * DM;
#pragma unroll
        for (int j = 0; j < 8; j++) {
            int e = tid + 256 * j;
            int i = e >> 5, c4 = e & 31;
            float4 v = *(const float4*)(psrc + i * DM + c4 * 4);
            pu[i * 129 + c4 * 4 + 0] = v.x;
            pu[i * 129 + c4 * 4 + 1] = v.y;
            pu[i * 129 + c4 * 4 + 2] = v.z;
            pu[i * 129 + c4 * 4 + 3] = v.w;
        }
        __syncthreads();
        float aP[4];
#pragma unroll
        for (int c = 0; c < 4; c++) aP[c] = a_pun[(size_t)b * TPUN + pc * 64 + pi * 4 + c];
        float C[4][4];
#pragma unroll
        for (int a = 0; a < 4; a++)
#pragma unroll
            for (int c = 0; c < 4; c++) C[a][c] = 0.f;
        for (int d4 = 0; d4 < 32; d4++) {
            float4 bq[4];
#pragma unroll
            for (int a = 0; a < 4; a++) bq[a] = *(const float4*)(bw + (ti * 4 + a) * 132 + d4 * 4);
#pragma unroll
            for (int dd = 0; dd < 4; dd++) {
                float pv[4];
#pragma unroll
                for (int c = 0; c < 4; c++) pv[c] = pu[(pi * 4 + c) * 129 + d4 * 4 + dd];
#pragma unroll
                for (int a = 0; a < 4; a++) {
                    float bvv = (dd == 0) ? bq[a].x : (dd == 1) ? bq[a].y : (dd == 2) ? bq[a].z : bq[a].w;
#pragma unroll
                    for (int c = 0; c < 4; c++) C[a][c] += bvv * pv[c];
                }
            }
        }
        float colv[4] = {-1e30f, -1e30f, -1e30f, -1e30f};
#pragma unroll
        for (int a = 0; a < 4; a++) {
            float rm = -1e30f;
#pragma unroll
            for (int c = 0; c < 4; c++) {
                float valv = C[a][c] + aB[a] + aP[c];
                rm = fmaxf(rm, valv);
                colv[c] = fmaxf(colv[c], valv);
            }
#pragma unroll
            for (int o = 1; o < 16; o <<= 1) rm = fmaxf(rm, __shfl_xor(rm, o, 64));
            mrun[a] = fmaxf(mrun[a], rm);
        }
#pragma unroll
        for (int c = 0; c < 4; c++) colred[(pi * 4 + c) * 16 + ti] = colv[c];
        __syncthreads();
        if (tid < 64) {
            float m = -1e30f;
#pragma unroll
            for (int k = 0; k < 16; k++) m = fmaxf(m, colred[tid * 16 + k]);
            colpart[((size_t)b * 8 + tt) * TPUN + pc * 64 + tid] = m;
        }
    }
    if (pi == 0) {
#pragma unroll
        for (int a = 0; a < 4; a++) m_t[(size_t)b * TBODY + t0 + ti * 4 + a] = mrun[a];
    }
}

__global__ __launch_bounds__(256) void k_colmax(const float* __restrict__ colpart,
                                                float* __restrict__ m_p) {
    int b = blockIdx.x, p = threadIdx.x;
    float m = -1e30f;
    for (int tt = 0; tt < 8; tt++) m = fmaxf(m, colpart[((size_t)b * 8 + tt) * TPUN + p]);
    m_p[(size_t)b * TPUN + p] = m;
}

// ---------------- softmax + attention-weighted feature sums ----------------
__global__ __launch_bounds__(256) void k_feat(const float* __restrict__ bodyM,
                                              const float* __restrict__ punM,
                                              const float* __restrict__ m_t,
                                              const float* __restrict__ m_p,
                                              float* __restrict__ feat) {
    int bidx = blockIdx.x;
    int b = bidx & (B - 1), which = bidx >> 7;
    int n = which ? TPUN : TBODY;
    const float* sc = which ? (m_p + (size_t)b * TPUN) : (m_t + (size_t)b * TBODY);
    const float* src = which ? (punM + (size_t)b * TPUN * DM) : (bodyM + (size_t)b * TBODY * DM);
    float* dst = feat + (size_t)b * 256 + which * DM;
    int tid = threadIdx.x;
    __shared__ float e_lds[TBODY];
    __shared__ float red[8];
    __shared__ float red2[256];
    float mx = -1e30f;
    for (int t = tid; t < n; t += 256) mx = fmaxf(mx, sc[t]);
    for (int o = 32; o; o >>= 1) mx = fmaxf(mx, __shfl_xor(mx, o, 64));
    if ((tid & 63) == 0) red[tid >> 6] = mx;
    __syncthreads();
    mx = fmaxf(fmaxf(red[0], red[1]), fmaxf(red[2], red[3]));
    float se = 0.f;
    for (int t = tid; t < n; t += 256) {
        float ev = __expf(sc[t] - mx);
        e_lds[t] = ev;
        se += ev;
    }
    for (int o = 32; o; o >>= 1) se += __shfl_xor(se, o, 64);
    if ((tid & 63) == 0) red[4 + (tid >> 6)] = se;
    __syncthreads();
    se = red[4] + red[5] + red[6] + red[7];
    float inv = 1.f / se;
    int d = tid & 127, half = tid >> 7;
    float acc = 0.f;
    for (int t = half; t < n; t += 2) acc += e_lds[t] * src[(size_t)t * DM + d];
    red2[tid] = acc;
    __syncthreads();
    if (tid < DM) dst[tid] = (red2[tid] + red2[tid + 128]) * inv;
}

// ---------------- out = feat @ Wd^T + bd ----------------
__global__ __launch_bounds__(256) void k_out(const float* __restrict__ feat,
                                             const float* __restrict__ Wd,
                                             const float* __restrict__ bd,
                                             float* __restrict__ outp) {
    int b = blockIdx.x, tid = threadIdx.x;
    float v = feat[(size_t)b * 256 + tid];
    __shared__ float red[12];
#pragma unroll
    for (int pol = 0; pol < 3; pol++) {
        float s = v * Wd[pol * 256 + tid];
        for (int o = 32; o; o >>= 1) s += __shfl_xor(s, o, 64);
        if ((tid & 63) == 0) red[pol * 4 + (tid >> 6)] = s;
    }
    __syncthreads();
    if (tid < 3) outp[b * 3 + tid] = red[tid * 4] + red[tid * 4 + 1] + red[tid * 4 + 2] + red[tid * 4 + 3] + bd[tid];
}

extern "C" void kernel_launch(void* const* d_in, const int* in_sizes, int n_in,
                              void* d_out, int out_size, void* d_ws, size_t ws_size,
                              hipStream_t stream) {
    const int* body_idx = (const int*)d_in[0];
    const int* pun_idx  = (const int*)d_in[1];
    const float* emb    = (const float*)d_in[2];
    const float* w_u    = (const float*)d_in[3];
    const float* Wd     = (const float*)d_in[4];
    const float* bd     = (const float*)d_in[5];
    const float* bWih_f = (const float*)d_in[6];
    const float* bWhh_f = (const float*)d_in[7];
    const float* bb_f   = (const float*)d_in[8];
    const float* bWih_b = (const float*)d_in[9];
    const float* bWhh_b = (const float*)d_in[10];
    const float* bb_b   = (const float*)d_in[11];
    const float* pWih_f = (const float*)d_in[12];
    const float* pWhh_f = (const float*)d_in[13];
    const float* pb_f   = (const float*)d_in[14];
    const float* pWih_b = (const float*)d_in[15];
    const float* pWhh_b = (const float*)d_in[16];
    const float* pb_b   = (const float*)d_in[17];

    char* ws = (char*)d_ws;
    float* xpB   = (float*)(ws + OFF_XPB);
    float* xpP   = (float*)(ws + OFF_XPP);
    float* bodyM = (float*)(ws + OFF_BODYM);
    float* punM  = (float*)(ws + OFF_PUNM);
    u16* embb    = (u16*)(ws + OFF_EMBB);
    u16* Wcb     = (u16*)(ws + OFF_WCB);
    u16* Wcp     = (u16*)(ws + OFF_WCP);
    float* biasb = (float*)(ws + OFF_BIASB);
    float* biasp = (float*)(ws + OFF_BIASP);
    int* lens    = (int*)(ws + OFF_LENS);
    float* a_body = (float*)(ws + OFF_ABODY);
    float* a_pun  = (float*)(ws + OFF_APUN);
    float* m_t    = (float*)(ws + OFF_MT);
    float* m_p    = (float*)(ws + OFF_MP);
    float* colpart = (float*)(ws + OFF_COLP);
    float* feat   = (float*)(ws + OFF_FEAT);
    float* outp   = (float*)d_out;

    k_lens<<<dim3(256), dim3(256), 0, stream>>>(body_idx, pun_idx, lens);
    k_prep_emb<<<dim3(62500), dim3(256), 0, stream>>>(emb, embb);
    k_prep_w<<<dim3(1284), dim3(256), 0, stream>>>(bWih_f, bWih_b, bb_f, bb_b,
                                                   pWih_f, pWih_b, pb_f, pb_b,
                                                   Wcb, Wcp, biasb, biasp);
    k_gemm<<<dim3(512, 4), dim3(256), 0, stream>>>(body_idx, embb, Wcb, biasb, xpB);
    k_gemm<<<dim3(256, 4), dim3(256), 0, stream>>>(pun_idx, embb, Wcp, biasp, xpP);
    hipMemsetAsync(ws + OFF_BODYM, 0, (size_t)(33554432u + 16777216u), stream);
    k_scan<<<dim3(512), dim3(512), 0, stream>>>(xpB, xpP, bodyM, punM, lens,
                                                bWhh_f, bWhh_b, pWhh_f, pWhh_b);
    k_rowdot<<<dim3(24576), dim3(256), 0, stream>>>(bodyM, punM, w_u, a_body, a_pun);
    k_align<<<dim3(8, 128), dim3(256), 0, stream>>>(bodyM, punM, a_body, a_pun, w_u, m_t, colpart);
    k_colmax<<<dim3(128), dim3(256), 0, stream>>>(colpart, m_p);
    k_feat<<<dim3(256), dim3(256), 0, stream>>>(bodyM, punM, m_t, m_p, feat);
    k_out<<<dim3(128), dim3(256), 0, stream>>>(feat, Wd, bd, outp);
}

// Round 6
// 675.174 us; speedup vs baseline: 1.2417x; 1.2417x over previous
//
#include <hip/hip_runtime.h>

// FGIAN BiLSTM+attention. R10: revert to R5's 4-wave/1-barrier k_scan core
// (best measured: 297us; R6/R8 LDS-broadcast=318-342, R9 K-split=447), then
// remove its two biggest per-step costs without touching the structure:
//  (a) 64 v_readlane -> row_ror DPP rotation: replica hq (lane l holds h-quad
//      l&15) rotated by row_ror:n pairs with PER-LANE PRE-ROTATED weight
//      groups (group n <-> k-quad (l16-n)&15). mov_dpp+fmac fuse to
//      v_fmac_f32_dpp (GCNDPPCombine), halving inner-loop issue.
//  (b) 4 ds_swizzle quad-gathers -> DPP quad_perm (QBC, HW-validated in R9):
//      removes 4 serial LDS round-trips (~130cy) from the act path.
// Everything outside k_scan unchanged.

#define B 128
#define TBODY 512
#define TPUN 256
#define EMB 300
#define EMBP 320
#define VOCAB 50000
#define HID 64
#define G4 256
#define NG 512
#define DM 128

typedef __attribute__((ext_vector_type(8))) short bf16x8;
typedef __attribute__((ext_vector_type(4))) float floatx4;
typedef unsigned short u16;

// ---- workspace layout (bytes) ----
#define OFF_XPB   0u                    // f32 [B*TBODY*NG] = 134217728
#define OFF_XPP   134217728u            // f32 [B*TPUN*NG]  =  67108864
#define OFF_BODYM 201326592u            // f32 [B*TBODY*DM] =  33554432
#define OFF_PUNM  234881024u            // f32 [B*TPUN*DM]  =  16777216
#define OFF_SMALL 251658240u
// overlays in xpB (dead after k_scan):
#define OFF_ABODY (OFF_XPB + 0u)
#define OFF_APUN  (OFF_XPB + 262144u)
#define OFF_MT    (OFF_XPB + 393216u)
#define OFF_MP    (OFF_XPB + 655360u)
#define OFF_COLP  (OFF_XPB + 786432u)
// overlays in bodyM/punM (dead until memset AFTER gemms):
#define OFF_EMBB  OFF_BODYM             // bf16 [VOCAB*EMBP] = 32000000
#define OFF_WCB   OFF_PUNM
#define OFF_WCP   (OFF_PUNM + 327680u)
#define OFF_BIASB (OFF_PUNM + 655360u)
#define OFF_BIASP (OFF_PUNM + 657408u)
#define OFF_LENS  OFF_SMALL
#define OFF_FEAT  (OFF_SMALL + 1024u)

__device__ inline u16 f2bf(float v) {
    unsigned int u = __float_as_uint(v);
    unsigned int r = (u + 0x7FFFu + ((u >> 16) & 1u)) >> 16;  // RNE
    return (u16)r;
}

__device__ inline void gload_lds16(const void* g, void* l) {
    __builtin_amdgcn_global_load_lds(
        (const __attribute__((address_space(1))) unsigned int*)g,
        (__attribute__((address_space(3))) unsigned int*)l, 16, 0, 0);
}

// quad_perm broadcast of quad-lane gg (0..3): ctrl = gg*0x55 (HW-ok, R9)
#define QBC(v, gg) __int_as_float(__builtin_amdgcn_update_dpp( \
    0, __float_as_int(v), (gg) * 0x55, 0xF, 0xF, true))
// row rotate: dst lane i = src lane (i-n)&15 within each 16-lane row
#define DPPR(v, n) __int_as_float(__builtin_amdgcn_update_dpp( \
    0, __float_as_int(v), 0x120 + (n), 0xF, 0xF, true))

// ---------------- lens ----------------
__global__ __launch_bounds__(256) void k_lens(const int* __restrict__ bidx,
                                              const int* __restrict__ pidx,
                                              int* __restrict__ lens) {
    int j = blockIdx.x, tid = threadIdx.x;
    const int* src; int n;
    if (j < B) { src = bidx + (size_t)j * TBODY; n = TBODY; }
    else       { src = pidx + (size_t)(j - B) * TPUN; n = TPUN; }
    int c = 0;
    for (int t = tid; t < n; t += 256) c += (src[t] != 0) ? 1 : 0;
    for (int o = 32; o; o >>= 1) c += __shfl_xor(c, o, 64);
    __shared__ int red[4];
    if ((tid & 63) == 0) red[tid >> 6] = c;
    __syncthreads();
    if (tid == 0) lens[j] = red[0] + red[1] + red[2] + red[3];
}

// ---------------- prep: emb -> bf16 padded ----------------
__global__ __launch_bounds__(256) void k_prep_emb(const float* __restrict__ emb,
                                                  u16* __restrict__ embb) {
    int e = blockIdx.x * 256 + threadIdx.x;  // exactly VOCAB*EMBP
    int row = e / EMBP, d = e - row * EMBP;
    float v = (d < EMB) ? emb[(size_t)row * EMB + d] : 0.f;
    embb[e] = f2bf(v);
}

// ---------------- prep: weights concat f/b -> bf16 padded + biases ----------------
__global__ __launch_bounds__(256) void k_prep_w(
    const float* __restrict__ bWih_f, const float* __restrict__ bWih_b,
    const float* __restrict__ bb_f, const float* __restrict__ bb_b,
    const float* __restrict__ pWih_f, const float* __restrict__ pWih_b,
    const float* __restrict__ pb_f, const float* __restrict__ pb_b,
    u16* __restrict__ Wcb, u16* __restrict__ Wcp,
    float* __restrict__ biasb, float* __restrict__ biasp) {
    int e = blockIdx.x * 256 + threadIdx.x;
    const int WSZ = NG * EMBP;  // 163840
    if (e < WSZ) {
        int g = e / EMBP, d = e - g * EMBP;
        float v = 0.f;
        if (d < EMB) v = (g < G4) ? bWih_f[g * EMB + d] : bWih_b[(g - G4) * EMB + d];
        Wcb[e] = f2bf(v);
    } else if (e < 2 * WSZ) {
        int ee = e - WSZ;
        int g = ee / EMBP, d = ee - g * EMBP;
        float v = 0.f;
        if (d < EMB) v = (g < G4) ? pWih_f[g * EMB + d] : pWih_b[(g - G4) * EMB + d];
        Wcp[ee] = f2bf(v);
    } else if (e < 2 * WSZ + NG) {
        int g = e - 2 * WSZ;
        biasb[g] = (g < G4) ? bb_f[g] : bb_b[g - G4];
    } else if (e < 2 * WSZ + 2 * NG) {
        int g = e - 2 * WSZ - NG;
        biasp[g] = (g < G4) ? pb_f[g] : pb_b[g - G4];
    }
}

// ---------------- 128x128 bf16 MFMA GEMM, global_load_lds staging ----------------
__global__ __launch_bounds__(256) void k_gemm(const int* __restrict__ idx,
                                              const u16* __restrict__ embb,
                                              const u16* __restrict__ Wc,
                                              const float* __restrict__ biasc,
                                              float* __restrict__ out) {
    __shared__ u16 As[128 * 32];
    __shared__ u16 Bs[128 * 32];
    int tid = threadIdx.x, wave = tid >> 6, lane = tid & 63;
    int m0 = blockIdx.x * 128, g0 = blockIdx.y * 128;

    const u16* agp[2]; const u16* bgp[2];
    u16* asd[2]; u16* bsd[2];
#pragma unroll
    for (int j = 0; j < 2; j++) {
        int rbase = wave * 32 + j * 16;
        int r = rbase + (lane >> 2);
        int clog = (lane & 3) ^ (r & 3);
        int arow = idx[m0 + r];
        agp[j] = embb + (size_t)arow * EMBP + clog * 8;
        bgp[j] = Wc + (size_t)(g0 + r) * EMBP + clog * 8;
        asd[j] = As + rbase * 32;
        bsd[j] = Bs + rbase * 32;
    }

    int l15 = lane & 15, quad = lane >> 4;
    int mt0 = (wave >> 1) * 4, nt0 = (wave & 1) * 4;
    const u16* ard[4]; const u16* brd[4];
#pragma unroll
    for (int a = 0; a < 4; a++) {
        int r = (mt0 + a) * 16 + l15;
        ard[a] = As + r * 32 + ((quad ^ (r & 3)) * 8);
        int n = (nt0 + a) * 16 + l15;
        brd[a] = Bs + n * 32 + ((quad ^ (n & 3)) * 8);
    }

    floatx4 acc[4][4];
#pragma unroll
    for (int a = 0; a < 4; a++)
#pragma unroll
        for (int c = 0; c < 4; c++) acc[a][c] = (floatx4){0.f, 0.f, 0.f, 0.f};

    for (int k0 = 0; k0 < EMBP; k0 += 32) {
#pragma unroll
        for (int j = 0; j < 2; j++) {
            gload_lds16(agp[j] + k0, asd[j]);
            gload_lds16(bgp[j] + k0, bsd[j]);
        }
        __syncthreads();
        bf16x8 af[4], bfr[4];
#pragma unroll
        for (int a = 0; a < 4; a++) { af[a] = *(const bf16x8*)ard[a]; bfr[a] = *(const bf16x8*)brd[a]; }
#pragma unroll
        for (int a = 0; a < 4; a++)
#pragma unroll
            for (int c = 0; c < 4; c++)
                acc[a][c] = __builtin_amdgcn_mfma_f32_16x16x32_bf16(af[a], bfr[c], acc[a][c], 0, 0, 0);
        __syncthreads();
    }

#pragma unroll
    for (int c = 0; c < 4; c++) {
        int gcol = g0 + (nt0 + c) * 16 + l15;
        float bv = biasc[gcol];
#pragma unroll
        for (int a = 0; a < 4; a++) {
            int row0 = m0 + (mt0 + a) * 16 + quad * 4;
#pragma unroll
            for (int rg = 0; rg < 4; rg++)
                out[(size_t)(row0 + rg) * NG + gcol] = acc[a][c][rg] + bv;
        }
    }
}

// ---------------- LSTM scans: 1 block (4 waves) per (seq,dir,b) ----------------
// wave w owns units 16w..16w+15; lane l: gate g=l&3, unit u=w*16+(l>>2).
// Replica ds_read_b128 gives lane l h-quad (l&15). Inner loop: 16 groups,
// group n rotates hq by row_ror:n (lane l then holds quad (l16-n)&15) and
// multiplies by PER-LANE PRE-ROTATED weight group n = k-quad ((l16-n)&15).
// mov_dpp+fmac fuse to v_fmac_f32_dpp. No readlanes, no ds_swizzle.
#define DECLWR(n) \
    float Wr##n##0, Wr##n##1, Wr##n##2, Wr##n##3; \
    { int qs_ = (((l16 - (n)) & 15) << 2); \
      Wr##n##0 = vw[qs_]; Wr##n##1 = vw[qs_ + 1]; \
      Wr##n##2 = vw[qs_ + 2]; Wr##n##3 = vw[qs_ + 3]; }
#define RORF(n) { \
    float rx_ = DPPR(hq.x, n), ry_ = DPPR(hq.y, n); \
    float rz_ = DPPR(hq.z, n), rw_ = DPPR(hq.w, n); \
    a0 = fmaf(rx_, Wr##n##0, a0); a1 = fmaf(ry_, Wr##n##1, a1); \
    a2 = fmaf(rz_, Wr##n##2, a2); a3 = fmaf(rw_, Wr##n##3, a3); }

__global__ __attribute__((amdgpu_flat_work_group_size(256, 256),
                          amdgpu_waves_per_eu(2, 2))) void k_scan(
    const float* __restrict__ xpB, const float* __restrict__ xpP,
    float* __restrict__ bodyM, float* __restrict__ punM,
    const int* __restrict__ lens,
    const float* __restrict__ bWhh_f, const float* __restrict__ bWhh_b,
    const float* __restrict__ pWhh_f, const float* __restrict__ pWhh_b) {
    int task = blockIdx.x, tid = threadIdx.x;
    int isPun = task >> 8;
    int sub = task & 255;
    int b = sub & 127, dir = sub >> 7;
    int T = isPun ? TPUN : TBODY;
    int len = lens[(isPun ? B : 0) + b];
    int w = tid >> 6, l = tid & 63;
    int g = l & 3, q = l >> 2;
    int u = w * 16 + q;
    int l16 = l & 15;
    const float* xp = (isPun ? xpP : xpB) + (size_t)b * T * NG + dir * G4;
    float* outp = (isPun ? punM : bodyM) + (size_t)b * T * DM + dir * HID;
    const float* Whh = isPun ? (dir ? pWhh_b : pWhh_f) : (dir ? bWhh_b : bWhh_f);

    // 64 weights (this lane's gate row) as named scalars, PRE-ROTATED so
    // group n matches row_ror:n of the replica hq. Volatile = load once.
    const volatile float* vw = Whh + (size_t)(g * 64 + u) * 64;
    DECLWR(0)  DECLWR(1)  DECLWR(2)  DECLWR(3)
    DECLWR(4)  DECLWR(5)  DECLWR(6)  DECLWR(7)
    DECLWR(8)  DECLWR(9)  DECLWR(10) DECLWR(11)
    DECLWR(12) DECLWR(13) DECLWR(14) DECLWR(15)

    __shared__ __align__(16) float hbuf[2][64];
    if (tid < 64) hbuf[0][tid] = 0.f;
    __syncthreads();
    if (len <= 0) return;

    const float* xg = xp + g * 64 + u;       // this lane's gate preact column
    float c = 0.f;
    float x_cur = xg[(size_t)(dir ? (len - 1) : 0) * NG];
    for (int s = 0; s < len; ++s) {
        int p = dir ? (len - 1 - s) : s;
        float xv = x_cur;
        // branchless prefetch of next step's x (clamped, always valid)
        int pn = dir ? (len - 2 - s) : (s + 1);
        pn = min(max(pn, 0), T - 1);
        x_cur = xg[(size_t)pn * NG];

        // replica read: lane l reads h[4*(l&15) .. +3] (4-row broadcast)
        float4 hq = *(const float4*)(&hbuf[s & 1][l16 * 4]);
        float a0 = xv, a1 = 0.f, a2 = 0.f, a3 = 0.f;
        // group 0: no rotation
        a0 = fmaf(hq.x, Wr00, a0); a1 = fmaf(hq.y, Wr01, a1);
        a2 = fmaf(hq.z, Wr02, a2); a3 = fmaf(hq.w, Wr03, a3);
        RORF(1)  RORF(2)  RORF(3)  RORF(4)  RORF(5)
        RORF(6)  RORF(7)  RORF(8)  RORF(9)  RORF(10)
        RORF(11) RORF(12) RORF(13) RORF(14) RORF(15)
        float pre = (a0 + a1) + (a2 + a3);
        // branchless: g==2 -> tanh(pre), else sigmoid(pre)
        bool isg = (g == 2);
        float t_in = isg ? (2.f * pre) : (-pre);
        float e = __expf(t_in);
        float r = __builtin_amdgcn_rcpf(1.f + e);
        float val = isg ? fmaf(-2.f, r, 1.f) : r;
        // quad gather i,f,g,o via DPP quad_perm (VALU, no LDS round-trip)
        float vi = QBC(val, 0);
        float vf = QBC(val, 1);
        float vg = QBC(val, 2);
        float vo = QBC(val, 3);
        c = fmaf(vf, c, vi * vg);
        float th = fmaf(-2.f, __builtin_amdgcn_rcpf(1.f + __expf(2.f * c)), 1.f);
        float h = vo * th;
        if (g == 0) {
            hbuf[(s & 1) ^ 1][u] = h;
            outp[(size_t)p * DM + u] = h;
        }
        __syncthreads();
    }
}

// ---------------- a_t = body_M.w1, b_p = pun_M.w2 (one wave per row) ----------------
__global__ __launch_bounds__(256) void k_rowdot(const float* __restrict__ bodyM,
                                                const float* __restrict__ punM,
                                                const float* __restrict__ w_u,
                                                float* __restrict__ a_body,
                                                float* __restrict__ a_pun) {
    int wid = (blockIdx.x * 256 + threadIdx.x) >> 6;
    int lane = threadIdx.x & 63;
    const int NB = B * TBODY;
    const float* src; const float* wv; float* dst;
    if (wid < NB) { src = bodyM + (size_t)wid * DM; wv = w_u; dst = a_body + wid; }
    else { src = punM + (size_t)(wid - NB) * DM; wv = w_u + DM; dst = a_pun + (wid - NB); }
    float2 v = ((const float2*)src)[lane];
    float2 w = ((const float2*)wv)[lane];
    float s = v.x * w.x + v.y * w.y;
    for (int o = 32; o; o >>= 1) s += __shfl_xor(s, o, 64);
    if (lane == 0) *dst = s;
}

// ---------------- align tile: m_t (full) + col partial maxes ----------------
__global__ __launch_bounds__(256) void k_align(
    const float* __restrict__ bodyM, const float* __restrict__ punM,
    const float* __restrict__ a_body, const float* __restrict__ a_pun,
    const float* __restrict__ w_u,
    float* __restrict__ m_t, float* __restrict__ colpart) {
    __shared__ float bw[64 * 132];
    __shared__ float pu[64 * 129];
    __shared__ float colred[64 * 16];
    int tid = threadIdx.x;
    int tt = blockIdx.x, b = blockIdx.y;
    int t0 = tt * 64;
    int ti = tid >> 4, pi = tid & 15;
    const float* w3 = w_u + 2 * DM;
    const float* bsrc = bodyM + ((size_t)b * TBODY + t0) * DM;
#pragma unroll
    for (int j = 0; j < 8; j++) {
        int e = tid + 256 * j;
        int i = e >> 5, c4 = e & 31;
        float4 v = *(const float4*)(bsrc + i * DM + c4 * 4);
        float4 wv = *(const float4*)(w3 + c4 * 4);
        v.x *= wv.x; v.y *= wv.y; v.z *= wv.z; v.w *= wv.w;
        *(float4*)(bw + i * 132 + c4 * 4) = v;
    }
    float aB[4];
#pragma unroll
    for (int a = 0; a < 4; a++) aB[a] = a_body[(size_t)b * TBODY + t0 + ti * 4 + a];
    float mrun[4] = {-1e30f, -1e30f, -1e30f, -1e30f};
    for (int pc = 0; pc < 4; pc++) {
        __syncthreads();
        const float* psrc = punM + ((size_t)b * TPUN + pc * 64) * DM;
#pragma unroll
        for (int j = 0; j < 8; j++) {
            int e = tid + 256 * j;
            int i = e >> 5, c4 = e & 31;
            float4 v = *(const float4*)(psrc + i * DM + c4 * 4);
            pu[i * 129 + c4 * 4 + 0] = v.x;
            pu[i * 129 + c4 * 4 + 1] = v.y;
            pu[i * 129 + c4 * 4 + 2] = v.z;
            pu[i * 129 + c4 * 4 + 3] = v.w;
        }
        __syncthreads();
        float aP[4];
#pragma unroll
        for (int c = 0; c < 4; c++) aP[c] = a_pun[(size_t)b * TPUN + pc * 64 + pi * 4 + c];
        float C[4][4];
#pragma unroll
        for (int a = 0; a < 4; a++)
#pragma unroll
            for (int c = 0; c < 4; c++) C[a][c] = 0.f;
        for (int d4 = 0; d4 < 32; d4++) {
            float4 bq[4];
#pragma unroll
            for (int a = 0; a < 4; a++) bq[a] = *(const float4*)(bw + (ti * 4 + a) * 132 + d4 * 4);
#pragma unroll
            for (int dd = 0; dd < 4; dd++) {
                float pv[4];
#pragma unroll
                for (int c = 0; c < 4; c++) pv[c] = pu[(pi * 4 + c) * 129 + d4 * 4 + dd];
#pragma unroll
                for (int a = 0; a < 4; a++) {
                    float bvv = (dd == 0) ? bq[a].x : (dd == 1) ? bq[a].y : (dd == 2) ? bq[a].z : bq[a].w;
#pragma unroll
                    for (int c = 0; c < 4; c++) C[a][c] += bvv * pv[c];
                }
            }
        }
        float colv[4] = {-1e30f, -1e30f, -1e30f, -1e30f};
#pragma unroll
        for (int a = 0; a < 4; a++) {
            float rm = -1e30f;
#pragma unroll
            for (int c = 0; c < 4; c++) {
                float valv = C[a][c] + aB[a] + aP[c];
                rm = fmaxf(rm, valv);
                colv[c] = fmaxf(colv[c], valv);
            }
#pragma unroll
            for (int o = 1; o < 16; o <<= 1) rm = fmaxf(rm, __shfl_xor(rm, o, 64));
            mrun[a] = fmaxf(mrun[a], rm);
        }
#pragma unroll
        for (int c = 0; c < 4; c++) colred[(pi * 4 + c) * 16 + ti] = colv[c];
        __syncthreads();
        if (tid < 64) {
            float m = -1e30f;
#pragma unroll
            for (int k = 0; k < 16; k++) m = fmaxf(m, colred[tid * 16 + k]);
            colpart[((size_t)b * 8 + tt) * TPUN + pc * 64 + tid] = m;
        }
    }
    if (pi == 0) {
#pragma unroll
        for (int a = 0; a < 4; a++) m_t[(size_t)b * TBODY + t0 + ti * 4 + a] = mrun[a];
    }
}

__global__ __launch_bounds__(256) void k_colmax(const float* __restrict__ colpart,
                                                float* __restrict__ m_p) {
    int b = blockIdx.x, p = threadIdx.x;
    float m = -1e30f;
    for (int tt = 0; tt < 8; tt++) m = fmaxf(m, colpart[((size_t)b * 8 + tt) * TPUN + p]);
    m_p[(size_t)b * TPUN + p] = m;
}

// ---------------- softmax + attention-weighted feature sums ----------------
__global__ __launch_bounds__(256) void k_feat(const float* __restrict__ bodyM,
                                              const float* __restrict__ punM,
                                              const float* __restrict__ m_t,
                                              const float* __restrict__ m_p,
                                              float* __restrict__ feat) {
    int bidx = blockIdx.x;
    int b = bidx & (B - 1), which = bidx >> 7;
    int n = which ? TPUN : TBODY;
    const float* sc = which ? (m_p + (size_t)b * TPUN) : (m_t + (size_t)b * TBODY);
    const float* src = which ? (punM + (size_t)b * TPUN * DM) : (bodyM + (size_t)b * TBODY * DM);
    float* dst = feat + (size_t)b * 256 + which * DM;
    int tid = threadIdx.x;
    __shared__ float e_lds[TBODY];
    __shared__ float red[8];
    __shared__ float red2[256];
    float mx = -1e30f;
    for (int t = tid; t < n; t += 256) mx = fmaxf(mx, sc[t]);
    for (int o = 32; o; o >>= 1) mx = fmaxf(mx, __shfl_xor(mx, o, 64));
    if ((tid & 63) == 0) red[tid >> 6] = mx;
    __syncthreads();
    mx = fmaxf(fmaxf(red[0], red[1]), fmaxf(red[2], red[3]));
    float se = 0.f;
    for (int t = tid; t < n; t += 256) {
        float ev = __expf(sc[t] - mx);
        e_lds[t] = ev;
        se += ev;
    }
    for (int o = 32; o; o >>= 1) se += __shfl_xor(se, o, 64);
    if ((tid & 63) == 0) red[4 + (tid >> 6)] = se;
    __syncthreads();
    se = red[4] + red[5] + red[6] + red[7];
    float inv = 1.f / se;
    int d = tid & 127, half = tid >> 7;
    float acc = 0.f;
    for (int t = half; t < n; t += 2) acc += e_lds[t] * src[(size_t)t * DM + d];
    red2[tid] = acc;
    __syncthreads();
    if (tid < DM) dst[tid] = (red2[tid] + red2[tid + 128]) * inv;
}

// ---------------- out = feat @ Wd^T + bd ----------------
__global__ __launch_bounds__(256) void k_out(const float* __restrict__ feat,
                                             const float* __restrict__ Wd,
                                             const float* __restrict__ bd,
                                             float* __restrict__ outp) {
    int b = blockIdx.x, tid = threadIdx.x;
    float v = feat[(size_t)b * 256 + tid];
    __shared__ float red[12];
#pragma unroll
    for (int pol = 0; pol < 3; pol++) {
        float s = v * Wd[pol * 256 + tid];
        for (int o = 32; o; o >>= 1) s += __shfl_xor(s, o, 64);
        if ((tid & 63) == 0) red[pol * 4 + (tid >> 6)] = s;
    }
    __syncthreads();
    if (tid < 3) outp[b * 3 + tid] = red[tid * 4] + red[tid * 4 + 1] + red[tid * 4 + 2] + red[tid * 4 + 3] + bd[tid];
}

extern "C" void kernel_launch(void* const* d_in, const int* in_sizes, int n_in,
                              void* d_out, int out_size, void* d_ws, size_t ws_size,
                              hipStream_t stream) {
    const int* body_idx = (const int*)d_in[0];
    const int* pun_idx  = (const int*)d_in[1];
    const float* emb    = (const float*)d_in[2];
    const float* w_u    = (const float*)d_in[3];
    const float* Wd     = (const float*)d_in[4];
    const float* bd     = (const float*)d_in[5];
    const float* bWih_f = (const float*)d_in[6];
    const float* bWhh_f = (const float*)d_in[7];
    const float* bb_f   = (const float*)d_in[8];
    const float* bWih_b = (const float*)d_in[9];
    const float* bWhh_b = (const float*)d_in[10];
    const float* bb_b   = (const float*)d_in[11];
    const float* pWih_f = (const float*)d_in[12];
    const float* pWhh_f = (const float*)d_in[13];
    const float* pb_f   = (const float*)d_in[14];
    const float* pWih_b = (const float*)d_in[15];
    const float* pWhh_b = (const float*)d_in[16];
    const float* pb_b   = (const float*)d_in[17];

    char* ws = (char*)d_ws;
    float* xpB   = (float*)(ws + OFF_XPB);
    float* xpP   = (float*)(ws + OFF_XPP);
    float* bodyM = (float*)(ws + OFF_BODYM);
    float* punM  = (float*)(ws + OFF_PUNM);
    u16* embb    = (u16*)(ws + OFF_EMBB);
    u16* Wcb     = (u16*)(ws + OFF_WCB);
    u16* Wcp     = (u16*)(ws + OFF_WCP);
    float* biasb = (float*)(ws + OFF_BIASB);
    float* biasp = (float*)(ws + OFF_BIASP);
    int* lens    = (int*)(ws + OFF_LENS);
    float* a_body = (float*)(ws + OFF_ABODY);
    float* a_pun  = (float*)(ws + OFF_APUN);
    float* m_t    = (float*)(ws + OFF_MT);
    float* m_p    = (float*)(ws + OFF_MP);
    float* colpart = (float*)(ws + OFF_COLP);
    float* feat   = (float*)(ws + OFF_FEAT);
    float* outp   = (float*)d_out;

    k_lens<<<dim3(256), dim3(256), 0, stream>>>(body_idx, pun_idx, lens);
    k_prep_emb<<<dim3(62500), dim3(256), 0, stream>>>(emb, embb);
    k_prep_w<<<dim3(1284), dim3(256), 0, stream>>>(bWih_f, bWih_b, bb_f, bb_b,
                                                   pWih_f, pWih_b, pb_f, pb_b,
                                                   Wcb, Wcp, biasb, biasp);
    k_gemm<<<dim3(512, 4), dim3(256), 0, stream>>>(body_idx, embb, Wcb, biasb, xpB);
    k_gemm<<<dim3(256, 4), dim3(256), 0, stream>>>(pun_idx, embb, Wcp, biasp, xpP);
    hipMemsetAsync(ws + OFF_BODYM, 0, (size_t)(33554432u + 16777216u), stream);
    k_scan<<<dim3(512), dim3(256), 0, stream>>>(xpB, xpP, bodyM, punM, lens,
                                                bWhh_f, bWhh_b, pWhh_f, pWhh_b);
    k_rowdot<<<dim3(24576), dim3(256), 0, stream>>>(bodyM, punM, w_u, a_body, a_pun);
    k_align<<<dim3(8, 128), dim3(256), 0, stream>>>(bodyM, punM, a_body, a_pun, w_u, m_t, colpart);
    k_colmax<<<dim3(128), dim3(256), 0, stream>>>(colpart, m_p);
    k_feat<<<dim3(256), dim3(256), 0, stream>>>(bodyM, punM, m_t, m_p, feat);
    k_out<<<dim3(128), dim3(256), 0, stream>>>(feat, Wd, bd, outp);
}

// Round 7
// 637.107 us; speedup vs baseline: 1.3159x; 1.0597x over previous
//
#include <hip/hip_runtime.h>

// FGIAN BiLSTM+attention. R11: R10 core + three targeted fixes from counters
// (step=1345cy, busy=795, stall=550):
//  (1) __syncthreads emits s_waitcnt vmcnt(0) before s_barrier -> every step's
//      barrier waited on that step's HBM x-prefetch (~900cy) and h-store ack.
//      Only cross-wave dep is the LDS h write: use raw
//      asm("s_waitcnt lgkmcnt(0); s_barrier") — no vmcnt drain.
//  (2) mov_dpp+fmac did NOT fuse (busy ~= 2x160instr). Emit v_fmac_f32_dpp
//      directly via inline asm — bit-identical, halves matvec issue.
//  (3) x prefetch deepened to 2 steps (unroll-2, xA/xB) so the load is hidden
//      at its use now that the barrier no longer drains it.
// Numerics identical to R10 (same ops, same order) -> absmax must match.

#define B 128
#define TBODY 512
#define TPUN 256
#define EMB 300
#define EMBP 320
#define VOCAB 50000
#define HID 64
#define G4 256
#define NG 512
#define DM 128

typedef __attribute__((ext_vector_type(8))) short bf16x8;
typedef __attribute__((ext_vector_type(4))) float floatx4;
typedef unsigned short u16;

// ---- workspace layout (bytes) ----
#define OFF_XPB   0u                    // f32 [B*TBODY*NG] = 134217728
#define OFF_XPP   134217728u            // f32 [B*TPUN*NG]  =  67108864
#define OFF_BODYM 201326592u            // f32 [B*TBODY*DM] =  33554432
#define OFF_PUNM  234881024u            // f32 [B*TPUN*DM]  =  16777216
#define OFF_SMALL 251658240u
// overlays in xpB (dead after k_scan):
#define OFF_ABODY (OFF_XPB + 0u)
#define OFF_APUN  (OFF_XPB + 262144u)
#define OFF_MT    (OFF_XPB + 393216u)
#define OFF_MP    (OFF_XPB + 655360u)
#define OFF_COLP  (OFF_XPB + 786432u)
// overlays in bodyM/punM (dead until memset AFTER gemms):
#define OFF_EMBB  OFF_BODYM             // bf16 [VOCAB*EMBP] = 32000000
#define OFF_WCB   OFF_PUNM
#define OFF_WCP   (OFF_PUNM + 327680u)
#define OFF_BIASB (OFF_PUNM + 655360u)
#define OFF_BIASP (OFF_PUNM + 657408u)
#define OFF_LENS  OFF_SMALL
#define OFF_FEAT  (OFF_SMALL + 1024u)

__device__ inline u16 f2bf(float v) {
    unsigned int u = __float_as_uint(v);
    unsigned int r = (u + 0x7FFFu + ((u >> 16) & 1u)) >> 16;  // RNE
    return (u16)r;
}

__device__ inline void gload_lds16(const void* g, void* l) {
    __builtin_amdgcn_global_load_lds(
        (const __attribute__((address_space(1))) unsigned int*)g,
        (__attribute__((address_space(3))) unsigned int*)l, 16, 0, 0);
}

// quad_perm broadcast of quad-lane gg (0..3): ctrl = gg*0x55 (HW-ok, R9/R10)
#define QBC(v, gg) __int_as_float(__builtin_amdgcn_update_dpp( \
    0, __float_as_int(v), (gg) * 0x55, 0xF, 0xF, true))

// ---------------- lens ----------------
__global__ __launch_bounds__(256) void k_lens(const int* __restrict__ bidx,
                                              const int* __restrict__ pidx,
                                              int* __restrict__ lens) {
    int j = blockIdx.x, tid = threadIdx.x;
    const int* src; int n;
    if (j < B) { src = bidx + (size_t)j * TBODY; n = TBODY; }
    else       { src = pidx + (size_t)(j - B) * TPUN; n = TPUN; }
    int c = 0;
    for (int t = tid; t < n; t += 256) c += (src[t] != 0) ? 1 : 0;
    for (int o = 32; o; o >>= 1) c += __shfl_xor(c, o, 64);
    __shared__ int red[4];
    if ((tid & 63) == 0) red[tid >> 6] = c;
    __syncthreads();
    if (tid == 0) lens[j] = red[0] + red[1] + red[2] + red[3];
}

// ---------------- prep: emb -> bf16 padded ----------------
__global__ __launch_bounds__(256) void k_prep_emb(const float* __restrict__ emb,
                                                  u16* __restrict__ embb) {
    int e = blockIdx.x * 256 + threadIdx.x;  // exactly VOCAB*EMBP
    int row = e / EMBP, d = e - row * EMBP;
    float v = (d < EMB) ? emb[(size_t)row * EMB + d] : 0.f;
    embb[e] = f2bf(v);
}

// ---------------- prep: weights concat f/b -> bf16 padded + biases ----------------
__global__ __launch_bounds__(256) void k_prep_w(
    const float* __restrict__ bWih_f, const float* __restrict__ bWih_b,
    const float* __restrict__ bb_f, const float* __restrict__ bb_b,
    const float* __restrict__ pWih_f, const float* __restrict__ pWih_b,
    const float* __restrict__ pb_f, const float* __restrict__ pb_b,
    u16* __restrict__ Wcb, u16* __restrict__ Wcp,
    float* __restrict__ biasb, float* __restrict__ biasp) {
    int e = blockIdx.x * 256 + threadIdx.x;
    const int WSZ = NG * EMBP;  // 163840
    if (e < WSZ) {
        int g = e / EMBP, d = e - g * EMBP;
        float v = 0.f;
        if (d < EMB) v = (g < G4) ? bWih_f[g * EMB + d] : bWih_b[(g - G4) * EMB + d];
        Wcb[e] = f2bf(v);
    } else if (e < 2 * WSZ) {
        int ee = e - WSZ;
        int g = ee / EMBP, d = ee - g * EMBP;
        float v = 0.f;
        if (d < EMB) v = (g < G4) ? pWih_f[g * EMB + d] : pWih_b[(g - G4) * EMB + d];
        Wcp[ee] = f2bf(v);
    } else if (e < 2 * WSZ + NG) {
        int g = e - 2 * WSZ;
        biasb[g] = (g < G4) ? bb_f[g] : bb_b[g - G4];
    } else if (e < 2 * WSZ + 2 * NG) {
        int g = e - 2 * WSZ - NG;
        biasp[g] = (g < G4) ? pb_f[g] : pb_b[g - G4];
    }
}

// ---------------- 128x128 bf16 MFMA GEMM, global_load_lds staging ----------------
__global__ __launch_bounds__(256) void k_gemm(const int* __restrict__ idx,
                                              const u16* __restrict__ embb,
                                              const u16* __restrict__ Wc,
                                              const float* __restrict__ biasc,
                                              float* __restrict__ out) {
    __shared__ u16 As[128 * 32];
    __shared__ u16 Bs[128 * 32];
    int tid = threadIdx.x, wave = tid >> 6, lane = tid & 63;
    int m0 = blockIdx.x * 128, g0 = blockIdx.y * 128;

    const u16* agp[2]; const u16* bgp[2];
    u16* asd[2]; u16* bsd[2];
#pragma unroll
    for (int j = 0; j < 2; j++) {
        int rbase = wave * 32 + j * 16;
        int r = rbase + (lane >> 2);
        int clog = (lane & 3) ^ (r & 3);
        int arow = idx[m0 + r];
        agp[j] = embb + (size_t)arow * EMBP + clog * 8;
        bgp[j] = Wc + (size_t)(g0 + r) * EMBP + clog * 8;
        asd[j] = As + rbase * 32;
        bsd[j] = Bs + rbase * 32;
    }

    int l15 = lane & 15, quad = lane >> 4;
    int mt0 = (wave >> 1) * 4, nt0 = (wave & 1) * 4;
    const u16* ard[4]; const u16* brd[4];
#pragma unroll
    for (int a = 0; a < 4; a++) {
        int r = (mt0 + a) * 16 + l15;
        ard[a] = As + r * 32 + ((quad ^ (r & 3)) * 8);
        int n = (nt0 + a) * 16 + l15;
        brd[a] = Bs + n * 32 + ((quad ^ (n & 3)) * 8);
    }

    floatx4 acc[4][4];
#pragma unroll
    for (int a = 0; a < 4; a++)
#pragma unroll
        for (int c = 0; c < 4; c++) acc[a][c] = (floatx4){0.f, 0.f, 0.f, 0.f};

    for (int k0 = 0; k0 < EMBP; k0 += 32) {
#pragma unroll
        for (int j = 0; j < 2; j++) {
            gload_lds16(agp[j] + k0, asd[j]);
            gload_lds16(bgp[j] + k0, bsd[j]);
        }
        __syncthreads();
        bf16x8 af[4], bfr[4];
#pragma unroll
        for (int a = 0; a < 4; a++) { af[a] = *(const bf16x8*)ard[a]; bfr[a] = *(const bf16x8*)brd[a]; }
#pragma unroll
        for (int a = 0; a < 4; a++)
#pragma unroll
            for (int c = 0; c < 4; c++)
                acc[a][c] = __builtin_amdgcn_mfma_f32_16x16x32_bf16(af[a], bfr[c], acc[a][c], 0, 0, 0);
        __syncthreads();
    }

#pragma unroll
    for (int c = 0; c < 4; c++) {
        int gcol = g0 + (nt0 + c) * 16 + l15;
        float bv = biasc[gcol];
#pragma unroll
        for (int a = 0; a < 4; a++) {
            int row0 = m0 + (mt0 + a) * 16 + quad * 4;
#pragma unroll
            for (int rg = 0; rg < 4; rg++)
                out[(size_t)(row0 + rg) * NG + gcol] = acc[a][c][rg] + bv;
        }
    }
}

// ---------------- LSTM scans: 1 block (4 waves) per (seq,dir,b) ----------------
// wave w owns units 16w..16w+15; lane l: gate g=l&3, unit u=w*16+(l>>2).
// Replica ds_read_b128 gives lane l h-quad (l&15). Matvec: 16 groups, group n
// uses v_fmac_f32_dpp row_ror:n (FUSED, src0=h rotated) against PER-LANE
// PRE-ROTATED weight group n = k-quad ((l16-n)&15). Barrier = raw
// lgkmcnt(0)+s_barrier (no vmcnt drain). x prefetched 2 steps deep (xA/xB).
#define DECLWR(n) \
    float Wr##n##0, Wr##n##1, Wr##n##2, Wr##n##3; \
    { int qs_ = (((l16 - (n)) & 15) << 2); \
      Wr##n##0 = vw[qs_]; Wr##n##1 = vw[qs_ + 1]; \
      Wr##n##2 = vw[qs_ + 2]; Wr##n##3 = vw[qs_ + 3]; }
#define FMACD(ACC, H, W, N) \
    asm("v_fmac_f32_dpp %0, %1, %2 row_ror:" #N " row_mask:0xf bank_mask:0xf" \
        : "+v"(ACC) : "v"(H), "v"(W));
#define RORF(n) { \
    FMACD(a0, hq.x, Wr##n##0, n) FMACD(a1, hq.y, Wr##n##1, n) \
    FMACD(a2, hq.z, Wr##n##2, n) FMACD(a3, hq.w, Wr##n##3, n) }

// one LSTM step; XR is used for this step then refilled with step S+2's x
#define SBODY(S, XR) { \
    int p_ = dir ? (len - 1 - (S)) : (S); \
    float xv = XR; \
    int pn_ = dir ? (len - 3 - (S)) : ((S) + 2); \
    pn_ = min(max(pn_, 0), T - 1); \
    XR = xg[(size_t)pn_ * NG]; \
    float4 hq = *(const float4*)(&hbuf[(S) & 1][l16 * 4]); \
    float a0 = xv, a1 = 0.f, a2 = 0.f, a3 = 0.f; \
    a0 = fmaf(hq.x, Wr00, a0); a1 = fmaf(hq.y, Wr01, a1); \
    a2 = fmaf(hq.z, Wr02, a2); a3 = fmaf(hq.w, Wr03, a3); \
    RORF(1)  RORF(2)  RORF(3)  RORF(4)  RORF(5) \
    RORF(6)  RORF(7)  RORF(8)  RORF(9)  RORF(10) \
    RORF(11) RORF(12) RORF(13) RORF(14) RORF(15) \
    float pre = (a0 + a1) + (a2 + a3); \
    bool isg = (g == 2); \
    float t_in = isg ? (2.f * pre) : (-pre); \
    float e_ = __expf(t_in); \
    float r_ = __builtin_amdgcn_rcpf(1.f + e_); \
    float val = isg ? fmaf(-2.f, r_, 1.f) : r_; \
    float vi = QBC(val, 0); \
    float vf = QBC(val, 1); \
    float vg = QBC(val, 2); \
    float vo = QBC(val, 3); \
    c = fmaf(vf, c, vi * vg); \
    float th = fmaf(-2.f, __builtin_amdgcn_rcpf(1.f + __expf(2.f * c)), 1.f); \
    float h = vo * th; \
    if (g == 0) { \
        hbuf[((S) & 1) ^ 1][u] = h; \
        outp[(size_t)p_ * DM + u] = h; \
    } \
    asm volatile("s_waitcnt lgkmcnt(0)\n\ts_barrier" ::: "memory"); }

__global__ __attribute__((amdgpu_flat_work_group_size(256, 256),
                          amdgpu_waves_per_eu(2, 2))) void k_scan(
    const float* __restrict__ xpB, const float* __restrict__ xpP,
    float* __restrict__ bodyM, float* __restrict__ punM,
    const int* __restrict__ lens,
    const float* __restrict__ bWhh_f, const float* __restrict__ bWhh_b,
    const float* __restrict__ pWhh_f, const float* __restrict__ pWhh_b) {
    int task = blockIdx.x, tid = threadIdx.x;
    int isPun = task >> 8;
    int sub = task & 255;
    int b = sub & 127, dir = sub >> 7;
    int T = isPun ? TPUN : TBODY;
    int len = lens[(isPun ? B : 0) + b];
    int w = tid >> 6, l = tid & 63;
    int g = l & 3, q = l >> 2;
    int u = w * 16 + q;
    int l16 = l & 15;
    const float* xp = (isPun ? xpP : xpB) + (size_t)b * T * NG + dir * G4;
    float* outp = (isPun ? punM : bodyM) + (size_t)b * T * DM + dir * HID;
    const float* Whh = isPun ? (dir ? pWhh_b : pWhh_f) : (dir ? bWhh_b : bWhh_f);

    // 64 weights (this lane's gate row) as named scalars, PRE-ROTATED so
    // group n matches row_ror:n of the replica hq. Volatile = load once.
    const volatile float* vw = Whh + (size_t)(g * 64 + u) * 64;
    DECLWR(0)  DECLWR(1)  DECLWR(2)  DECLWR(3)
    DECLWR(4)  DECLWR(5)  DECLWR(6)  DECLWR(7)
    DECLWR(8)  DECLWR(9)  DECLWR(10) DECLWR(11)
    DECLWR(12) DECLWR(13) DECLWR(14) DECLWR(15)

    __shared__ __align__(16) float hbuf[2][64];
    if (tid < 64) hbuf[0][tid] = 0.f;
    __syncthreads();
    if (len <= 0) return;

    const float* xg = xp + g * 64 + u;       // this lane's gate preact column
    float c = 0.f;
    // 2-deep x prefetch: xA for even steps, xB for odd steps
    int p0 = dir ? (len - 1) : 0;
    int p1 = dir ? (len - 2) : 1;
    p1 = min(max(p1, 0), T - 1);
    float xA = xg[(size_t)p0 * NG];
    float xB = xg[(size_t)p1 * NG];
    int s = 0;
    for (; s + 1 < len; s += 2) {
        SBODY(s, xA)
        SBODY(s + 1, xB)
    }
    if (s < len) { SBODY(s, xA) }
}

// ---------------- a_t = body_M.w1, b_p = pun_M.w2 (one wave per row) ----------------
__global__ __launch_bounds__(256) void k_rowdot(const float* __restrict__ bodyM,
                                                const float* __restrict__ punM,
                                                const float* __restrict__ w_u,
                                                float* __restrict__ a_body,
                                                float* __restrict__ a_pun) {
    int wid = (blockIdx.x * 256 + threadIdx.x) >> 6;
    int lane = threadIdx.x & 63;
    const int NB = B * TBODY;
    const float* src; const float* wv; float* dst;
    if (wid < NB) { src = bodyM + (size_t)wid * DM; wv = w_u; dst = a_body + wid; }
    else { src = punM + (size_t)(wid - NB) * DM; wv = w_u + DM; dst = a_pun + (wid - NB); }
    float2 v = ((const float2*)src)[lane];
    float2 w = ((const float2*)wv)[lane];
    float s = v.x * w.x + v.y * w.y;
    for (int o = 32; o; o >>= 1) s += __shfl_xor(s, o, 64);
    if (lane == 0) *dst = s;
}

// ---------------- align tile: m_t (full) + col partial maxes ----------------
__global__ __launch_bounds__(256) void k_align(
    const float* __restrict__ bodyM, const float* __restrict__ punM,
    const float* __restrict__ a_body, const float* __restrict__ a_pun,
    const float* __restrict__ w_u,
    float* __restrict__ m_t, float* __restrict__ colpart) {
    __shared__ float bw[64 * 132];
    __shared__ float pu[64 * 129];
    __shared__ float colred[64 * 16];
    int tid = threadIdx.x;
    int tt = blockIdx.x, b = blockIdx.y;
    int t0 = tt * 64;
    int ti = tid >> 4, pi = tid & 15;
    const float* w3 = w_u + 2 * DM;
    const float* bsrc = bodyM + ((size_t)b * TBODY + t0) * DM;
#pragma unroll
    for (int j = 0; j < 8; j++) {
        int e = tid + 256 * j;
        int i = e >> 5, c4 = e & 31;
        float4 v = *(const float4*)(bsrc + i * DM + c4 * 4);
        float4 wv = *(const float4*)(w3 + c4 * 4);
        v.x *= wv.x; v.y *= wv.y; v.z *= wv.z; v.w *= wv.w;
        *(float4*)(bw + i * 132 + c4 * 4) = v;
    }
    float aB[4];
#pragma unroll
    for (int a = 0; a < 4; a++) aB[a] = a_body[(size_t)b * TBODY + t0 + ti * 4 + a];
    float mrun[4] = {-1e30f, -1e30f, -1e30f, -1e30f};
    for (int pc = 0; pc < 4; pc++) {
        __syncthreads();
        const float* psrc = punM + ((size_t)b * TPUN + pc * 64) * DM;
#pragma unroll
        for (int j = 0; j < 8; j++) {
            int e = tid + 256 * j;
            int i = e >> 5, c4 = e & 31;
            float4 v = *(const float4*)(psrc + i * DM + c4 * 4);
            pu[i * 129 + c4 * 4 + 0] = v.x;
            pu[i * 129 + c4 * 4 + 1] = v.y;
            pu[i * 129 + c4 * 4 + 2] = v.z;
            pu[i * 129 + c4 * 4 + 3] = v.w;
        }
        __syncthreads();
        float aP[4];
#pragma unroll
        for (int c = 0; c < 4; c++) aP[c] = a_pun[(size_t)b * TPUN + pc * 64 + pi * 4 + c];
        float C[4][4];
#pragma unroll
        for (int a = 0; a < 4; a++)
#pragma unroll
            for (int c = 0; c < 4; c++) C[a][c] = 0.f;
        for (int d4 = 0; d4 < 32; d4++) {
            float4 bq[4];
#pragma unroll
            for (int a = 0; a < 4; a++) bq[a] = *(const float4*)(bw + (ti * 4 + a) * 132 + d4 * 4);
#pragma unroll
            for (int dd = 0; dd < 4; dd++) {
                float pv[4];
#pragma unroll
                for (int c = 0; c < 4; c++) pv[c] = pu[(pi * 4 + c) * 129 + d4 * 4 + dd];
#pragma unroll
                for (int a = 0; a < 4; a++) {
                    float bvv = (dd == 0) ? bq[a].x : (dd == 1) ? bq[a].y : (dd == 2) ? bq[a].z : bq[a].w;
#pragma unroll
                    for (int c = 0; c < 4; c++) C[a][c] += bvv * pv[c];
                }
            }
        }
        float colv[4] = {-1e30f, -1e30f, -1e30f, -1e30f};
#pragma unroll
        for (int a = 0; a < 4; a++) {
            float rm = -1e30f;
#pragma unroll
            for (int c = 0; c < 4; c++) {
                float valv = C[a][c] + aB[a] + aP[c];
                rm = fmaxf(rm, valv);
                colv[c] = fmaxf(colv[c], valv);
            }
#pragma unroll
            for (int o = 1; o < 16; o <<= 1) rm = fmaxf(rm, __shfl_xor(rm, o, 64));
            mrun[a] = fmaxf(mrun[a], rm);
        }
#pragma unroll
        for (int c = 0; c < 4; c++) colred[(pi * 4 + c) * 16 + ti] = colv[c];
        __syncthreads();
        if (tid < 64) {
            float m = -1e30f;
#pragma unroll
            for (int k = 0; k < 16; k++) m = fmaxf(m, colred[tid * 16 + k]);
            colpart[((size_t)b * 8 + tt) * TPUN + pc * 64 + tid] = m;
        }
    }
    if (pi == 0) {
#pragma unroll
        for (int a = 0; a < 4; a++) m_t[(size_t)b * TBODY + t0 + ti * 4 + a] = mrun[a];
    }
}

__global__ __launch_bounds__(256) void k_colmax(const float* __restrict__ colpart,
                                                float* __restrict__ m_p) {
    int b = blockIdx.x, p = threadIdx.x;
    float m = -1e30f;
    for (int tt = 0; tt < 8; tt++) m = fmaxf(m, colpart[((size_t)b * 8 + tt) * TPUN + p]);
    m_p[(size_t)b * TPUN + p] = m;
}

// ---------------- softmax + attention-weighted feature sums ----------------
__global__ __launch_bounds__(256) void k_feat(const float* __restrict__ bodyM,
                                              const float* __restrict__ punM,
                                              const float* __restrict__ m_t,
                                              const float* __restrict__ m_p,
                                              float* __restrict__ feat) {
    int bidx = blockIdx.x;
    int b = bidx & (B - 1), which = bidx >> 7;
    int n = which ? TPUN : TBODY;
    const float* sc = which ? (m_p + (size_t)b * TPUN) : (m_t + (size_t)b * TBODY);
    const float* src = which ? (punM + (size_t)b * TPUN * DM) : (bodyM + (size_t)b * TBODY * DM);
    float* dst = feat + (size_t)b * 256 + which * DM;
    int tid = threadIdx.x;
    __shared__ float e_lds[TBODY];
    __shared__ float red[8];
    __shared__ float red2[256];
    float mx = -1e30f;
    for (int t = tid; t < n; t += 256) mx = fmaxf(mx, sc[t]);
    for (int o = 32; o; o >>= 1) mx = fmaxf(mx, __shfl_xor(mx, o, 64));
    if ((tid & 63) == 0) red[tid >> 6] = mx;
    __syncthreads();
    mx = fmaxf(fmaxf(red[0], red[1]), fmaxf(red[2], red[3]));
    float se = 0.f;
    for (int t = tid; t < n; t += 256) {
        float ev = __expf(sc[t] - mx);
        e_lds[t] = ev;
        se += ev;
    }
    for (int o = 32; o; o >>= 1) se += __shfl_xor(se, o, 64);
    if ((tid & 63) == 0) red[4 + (tid >> 6)] = se;
    __syncthreads();
    se = red[4] + red[5] + red[6] + red[7];
    float inv = 1.f / se;
    int d = tid & 127, half = tid >> 7;
    float acc = 0.f;
    for (int t = half; t < n; t += 2) acc += e_lds[t] * src[(size_t)t * DM + d];
    red2[tid] = acc;
    __syncthreads();
    if (tid < DM) dst[tid] = (red2[tid] + red2[tid + 128]) * inv;
}

// ---------------- out = feat @ Wd^T + bd ----------------
__global__ __launch_bounds__(256) void k_out(const float* __restrict__ feat,
                                             const float* __restrict__ Wd,
                                             const float* __restrict__ bd,
                                             float* __restrict__ outp) {
    int b = blockIdx.x, tid = threadIdx.x;
    float v = feat[(size_t)b * 256 + tid];
    __shared__ float red[12];
#pragma unroll
    for (int pol = 0; pol < 3; pol++) {
        float s = v * Wd[pol * 256 + tid];
        for (int o = 32; o; o >>= 1) s += __shfl_xor(s, o, 64);
        if ((tid & 63) == 0) red[pol * 4 + (tid >> 6)] = s;
    }
    __syncthreads();
    if (tid < 3) outp[b * 3 + tid] = red[tid * 4] + red[tid * 4 + 1] + red[tid * 4 + 2] + red[tid * 4 + 3] + bd[tid];
}

extern "C" void kernel_launch(void* const* d_in, const int* in_sizes, int n_in,
                              void* d_out, int out_size, void* d_ws, size_t ws_size,
                              hipStream_t stream) {
    const int* body_idx = (const int*)d_in[0];
    const int* pun_idx  = (const int*)d_in[1];
    const float* emb    = (const float*)d_in[2];
    const float* w_u    = (const float*)d_in[3];
    const float* Wd     = (const float*)d_in[4];
    const float* bd     = (const float*)d_in[5];
    const float* bWih_f = (const float*)d_in[6];
    const float* bWhh_f = (const float*)d_in[7];
    const float* bb_f   = (const float*)d_in[8];
    const float* bWih_b = (const float*)d_in[9];
    const float* bWhh_b = (const float*)d_in[10];
    const float* bb_b   = (const float*)d_in[11];
    const float* pWih_f = (const float*)d_in[12];
    const float* pWhh_f = (const float*)d_in[13];
    const float* pb_f   = (const float*)d_in[14];
    const float* pWih_b = (const float*)d_in[15];
    const float* pWhh_b = (const float*)d_in[16];
    const float* pb_b   = (const float*)d_in[17];

    char* ws = (char*)d_ws;
    float* xpB   = (float*)(ws + OFF_XPB);
    float* xpP   = (float*)(ws + OFF_XPP);
    float* bodyM = (float*)(ws + OFF_BODYM);
    float* punM  = (float*)(ws + OFF_PUNM);
    u16* embb    = (u16*)(ws + OFF_EMBB);
    u16* Wcb     = (u16*)(ws + OFF_WCB);
    u16* Wcp     = (u16*)(ws + OFF_WCP);
    float* biasb = (float*)(ws + OFF_BIASB);
    float* biasp = (float*)(ws + OFF_BIASP);
    int* lens    = (int*)(ws + OFF_LENS);
    float* a_body = (float*)(ws + OFF_ABODY);
    float* a_pun  = (float*)(ws + OFF_APUN);
    float* m_t    = (float*)(ws + OFF_MT);
    float* m_p    = (float*)(ws + OFF_MP);
    float* colpart = (float*)(ws + OFF_COLP);
    float* feat   = (float*)(ws + OFF_FEAT);
    float* outp   = (float*)d_out;

    k_lens<<<dim3(256), dim3(256), 0, stream>>>(body_idx, pun_idx, lens);
    k_prep_emb<<<dim3(62500), dim3(256), 0, stream>>>(emb, embb);
    k_prep_w<<<dim3(1284), dim3(256), 0, stream>>>(bWih_f, bWih_b, bb_f, bb_b,
                                                   pWih_f, pWih_b, pb_f, pb_b,
                                                   Wcb, Wcp, biasb, biasp);
    k_gemm<<<dim3(512, 4), dim3(256), 0, stream>>>(body_idx, embb, Wcb, biasb, xpB);
    k_gemm<<<dim3(256, 4), dim3(256), 0, stream>>>(pun_idx, embb, Wcp, biasp, xpP);
    hipMemsetAsync(ws + OFF_BODYM, 0, (size_t)(33554432u + 16777216u), stream);
    k_scan<<<dim3(512), dim3(256), 0, stream>>>(xpB, xpP, bodyM, punM, lens,
                                                bWhh_f, bWhh_b, pWhh_f, pWhh_b);
    k_rowdot<<<dim3(24576), dim3(256), 0, stream>>>(bodyM, punM, w_u, a_body, a_pun);
    k_align<<<dim3(8, 128), dim3(256), 0, stream>>>(bodyM, punM, a_body, a_pun, w_u, m_t, colpart);
    k_colmax<<<dim3(128), dim3(256), 0, stream>>>(colpart, m_p);
    k_feat<<<dim3(256), dim3(256), 0, stream>>>(bodyM, punM, m_t, m_p, feat);
    k_out<<<dim3(128), dim3(256), 0, stream>>>(feat, Wd, bd, outp);
}